// Round 9
// baseline (837.077 us; speedup 1.0000x reference)
//
#include <hip/hip_runtime.h>

typedef __attribute__((ext_vector_type(8))) __bf16 bf16x8;
typedef __attribute__((ext_vector_type(4))) float f32x4;
typedef unsigned short u16;
typedef __attribute__((ext_vector_type(4))) u16 u16x4;
typedef __attribute__((ext_vector_type(8))) u16 u16x8;

#define MASKVAL -3.0e38f
#define MINIT   -1.0e38f
#define LOG2E 1.4426950408889634f

__device__ inline f32x4 zero4() { f32x4 v; v[0]=0.f; v[1]=0.f; v[2]=0.f; v[3]=0.f; return v; }

__device__ inline u16 bf16bits(float x) {
    union { __bf16 h; u16 u; } cv; cv.h = (__bf16)x; return cv.u;
}
__device__ inline float bits2f(u16 b) {
    union { unsigned u; float f; } cv; cv.u = ((unsigned)b) << 16; return cv.f;
}

// async 16B/lane global -> LDS (lds dest = wave-uniform base + lane*16)
__device__ inline void load_lds16(const u16* g, u16* l) {
    __builtin_amdgcn_global_load_lds((const __attribute__((address_space(1))) void*)g,
                                     (__attribute__((address_space(3))) void*)l, 16, 0, 0);
}

// ---------------------------------------------------------------------------
// Convert W_Q (pre-scaled by 1/sqrt(512)), W_K, W_V to bf16 concat [1536][512].
// ---------------------------------------------------------------------------
__global__ void convert_w(const float* __restrict__ WQ, const float* __restrict__ WK,
                          const float* __restrict__ WV, u16* __restrict__ Wb)
{
    const float qscale = 0.044194173824159216f;  // 1/sqrt(512)
    const int i8 = (blockIdx.x * 256 + threadIdx.x) * 8;
    const int seg = i8 >> 18;                    // 262144 els per W
    const int within = i8 & 262143;
    const float* src = (seg == 0) ? WQ : (seg == 1) ? WK : WV;
    const float sc = (seg == 0) ? qscale : 1.0f;
    f32x4 a = *(const f32x4*)(src + within);
    f32x4 b = *(const f32x4*)(src + within + 4);
    bf16x8 v;
    v[0]=(__bf16)(a[0]*sc); v[1]=(__bf16)(a[1]*sc); v[2]=(__bf16)(a[2]*sc); v[3]=(__bf16)(a[3]*sc);
    v[4]=(__bf16)(b[0]*sc); v[5]=(__bf16)(b[1]*sc); v[6]=(__bf16)(b[2]*sc); v[7]=(__bf16)(b[3]*sc);
    *(bf16x8*)(Wb + i8) = v;
}

// ---------------------------------------------------------------------------
// Convert X f32 -> bf16. 16384*512 = 8,388,608 els = 4096 blocks x 256 x 8.
// ---------------------------------------------------------------------------
__global__ void convert_x(const float* __restrict__ X, u16* __restrict__ Xb)
{
    const size_t i8 = ((size_t)blockIdx.x * 256 + threadIdx.x) * 8;
    f32x4 a = *(const f32x4*)(X + i8);
    f32x4 b = *(const f32x4*)(X + i8 + 4);
    bf16x8 v;
    v[0]=(__bf16)a[0]; v[1]=(__bf16)a[1]; v[2]=(__bf16)a[2]; v[3]=(__bf16)a[3];
    v[4]=(__bf16)b[0]; v[5]=(__bf16)b[1]; v[6]=(__bf16)b[2]; v[7]=(__bf16)b[3];
    *(bf16x8*)(Xb + i8) = v;
}

// ---------------------------------------------------------------------------
// GEMM: Q/K [16384][512] bf16; V^T tiled [b][u32 (128)][512 d][32 k] bf16.
// A = Xb bf16, B = Wb bf16, both staged via global_load_lds width-16.
// 128x128 tile, BK=32, 4 waves. grid = (12, 128): x: 0-3 Q, 4-7 K, 8-11 V.
// ---------------------------------------------------------------------------
__global__ __launch_bounds__(256, 2)
void gemm_qkv(const u16* __restrict__ Xb, const u16* __restrict__ Wb,
              u16* __restrict__ Qb, u16* __restrict__ Kb, u16* __restrict__ Vt)
{
    __shared__ u16 As[128*32];
    __shared__ u16 Bs[128*32];
    const int t  = threadIdx.x;
    const int l  = t & 63;
    const int w  = t >> 6;
    const int c  = l & 15;
    const int qd = l >> 4;
    const int m0 = blockIdx.y * 128;
    const int nblk = blockIdx.x;
    const int n0 = nblk * 128;                  // row into Wb[1536]
    const int seg = nblk >> 2;
    const int nw0 = (nblk & 3) * 128;           // feature offset within a W
    const int wm = w >> 1, wn = w & 1;
    const int lr = l >> 2;                      // 0..15 row-within-instr
    const int lc = (l & 3) * 8;                 // 8-el chunk

    f32x4 acc[4][4];
    #pragma unroll
    for (int i = 0; i < 4; i++)
        #pragma unroll
        for (int j = 0; j < 4; j++) acc[i][j] = zero4();

    for (int kk = 0; kk < 512; kk += 32) {
        #pragma unroll
        for (int i = 0; i < 2; ++i) {
            const int r0 = w*32 + i*16;
            load_lds16(&Xb[(size_t)(m0 + r0 + lr)*512 + kk + lc], &As[r0*32]);
            load_lds16(&Wb[(size_t)(n0 + r0 + lr)*512 + kk + lc], &Bs[r0*32]);
        }
        __syncthreads();
        bf16x8 af[4], bfr[4];
        #pragma unroll
        for (int mt = 0; mt < 4; mt++) af[mt]  = *(const bf16x8*)&As[(wm*64 + mt*16 + c)*32 + qd*8];
        #pragma unroll
        for (int nt = 0; nt < 4; nt++) bfr[nt] = *(const bf16x8*)&Bs[(wn*64 + nt*16 + c)*32 + qd*8];
        #pragma unroll
        for (int mt = 0; mt < 4; mt++)
            #pragma unroll
            for (int nt = 0; nt < 4; nt++)
                acc[mt][nt] = __builtin_amdgcn_mfma_f32_16x16x32_bf16(af[mt], bfr[nt], acc[mt][nt], 0, 0, 0);
        __syncthreads();
    }

    #pragma unroll
    for (int mt = 0; mt < 4; mt++) {
        #pragma unroll
        for (int nt = 0; nt < 4; nt++) {
            const int gm0 = m0 + wm*64 + mt*16 + qd*4;       // token row of reg 0
            const int gn  = nw0 + wn*64 + nt*16 + c;         // feature 0..511
            if (seg == 0) {
                #pragma unroll
                for (int r = 0; r < 4; r++)
                    Qb[(size_t)(gm0 + r)*512 + gn] = bf16bits(acc[mt][nt][r]);
            } else if (seg == 1) {
                #pragma unroll
                for (int r = 0; r < 4; r++)
                    Kb[(size_t)(gm0 + r)*512 + gn] = bf16bits(acc[mt][nt][r]);
            } else {
                const int bb   = gm0 >> 12;
                const int ss   = gm0 & 4095;
                const int unit = ss >> 5;                    // 32-key unit
                const int kl   = ss & 31;                    // 4-aligned
                u16x4 pk;
                pk[0] = bf16bits(acc[mt][nt][0]);
                pk[1] = bf16bits(acc[mt][nt][1]);
                pk[2] = bf16bits(acc[mt][nt][2]);
                pk[3] = bf16bits(acc[mt][nt][3]);
                *(u16x4*)&Vt[((size_t)(bb*128 + unit)*512 + gn)*32 + kl] = pk;
            }
        }
    }
}

// ---------------------------------------------------------------------------
// Flash attention chunk v9, causal. R7 chunking (1024 blocks, 4 chunks/qt,
// heavy-first, dynamic backfill keeps 2 blocks/CU) + PHASE-MIXED iteration:
// PV(it-1) MFMAs interleaved into the S^T(it) loop (independent streams fill
// the matrix pipe's dependency gaps); softmax after the mixed loop; V(it)
// loads issued at iteration END (full-unit latency cover, same registers);
// K staging issued right after the barrier.
// Unit = 32 keys; S^T = K Q^T per 16-row strip; PV d-split with P broadcast
// via LDS dbuf; V per-wave from global (b128, L2-hot); frozen-m softmax.
// ---------------------------------------------------------------------------
__global__ __launch_bounds__(256, 2)
void attn_chunk(const u16* __restrict__ Qb, const u16* __restrict__ Kb,
                const u16* __restrict__ Vt, u16* __restrict__ Op,
                float* __restrict__ Mp, float* __restrict__ Lp)
{
    __shared__ u16 Ks[2][32*520];   // 66,560 B  K rows padded 520 (1KB contiguous)
    __shared__ u16 Ps[2][64*40];    // 10,240 B  P[row][32 keys + pad 8]
    __shared__ float Al[2][64];     //  512 B    per-row alpha (slow path)
    __shared__ unsigned Fl[2][4];   //   32 B    per-strip rescale flag

    const int t  = threadIdx.x;
    const int l  = t & 63;
    const int w  = t >> 6;
    const int c  = l & 15;
    const int qd = l >> 4;
    const int x  = blockIdx.x;
    const int qt = 63 - (x >> 4);
    const int j  = (x >> 2) & 3;
    const int b  = x & 3;
    const int U  = 2*qt + 2;                 // 32-key units total
    const int uc = (U + 3) >> 2;
    const int it0 = j * uc;
    if (it0 >= U) return;
    const int it1 = min(U, it0 + uc) - 1;
    const int q0 = qt * 64;
    const int itSkip = 2*qt + (w >> 1);      // last unit with any valid key for strip w

    // Q fragments (B-operand: n=row=c, k=qd*8+jj), register-resident
    bf16x8 qf[16];
    {
        const size_t qrow = (size_t)(b*4096 + q0 + w*16 + c);
        #pragma unroll
        for (int ks = 0; ks < 16; ++ks)
            qf[ks] = *(const bf16x8*)&Qb[qrow*512 + ks*32 + qd*8];
    }

    f32x4 o[8][4];                  // [dt][rt]: d = w*128+dt*16+qd*4+r, row = rt*16+c
    #pragma unroll
    for (int dt = 0; dt < 8; dt++)
        #pragma unroll
        for (int rt = 0; rt < 4; rt++) o[dt][rt] = zero4();
    float m_c = MINIT, l_c = 0.f;
    bf16x8 vf[8];                   // V fragments for NEXT iteration's PV

    const u16* Kg = Kb + (size_t)(b*4096)*512;
    const u16* Vg = Vt + (size_t)(b*128)*16384;

    // prologue: stage K(it0); wave w stages key-rows [8w, 8w+8)
    #pragma unroll
    for (int i = 0; i < 8; i++) {
        const int row = w*8 + i;
        load_lds16(Kg + ((size_t)(it0*32 + row))*512 + l*8, &Ks[0][row*520]);
    }

    for (int it = it0; it <= it1 + 1; ++it) {
        const int pb = (it - it0) & 1;
        __syncthreads();            // K(it) staged; P(it-1)/Al/Fl published

        // ---- issue K staging (it+1) immediately (targets other buffer)
        if (it < it1) {
            #pragma unroll
            for (int i = 0; i < 8; i++) {
                const int row = w*8 + i;
                load_lds16(Kg + ((size_t)((it+1)*32 + row))*512 + l*8, &Ks[pb^1][row*520]);
            }
        }

        // ---- P(it-1) fragments + rescale o (data ready at barrier)
        const bool haveP = (it > it0);
        bf16x8 pfr[4];
        if (haveP) {
            const int ppb = pb ^ 1;
            #pragma unroll
            for (int rt = 0; rt < 4; rt++)
                pfr[rt] = *(const bf16x8*)&Ps[ppb][(rt*16 + c)*40 + qd*8];
            #pragma unroll
            for (int rt = 0; rt < 4; rt++) {
                if (Fl[ppb][rt]) {
                    const float al = Al[ppb][rt*16 + c];
                    #pragma unroll
                    for (int dt = 0; dt < 8; dt++) {
                        o[dt][rt][0] *= al; o[dt][rt][1] *= al;
                        o[dt][rt][2] *= al; o[dt][rt][3] *= al;
                    }
                }
            }
        }

        if (it <= it1 && it <= itSkip) {
            // ---- phase-mixed: S^T(it) interleaved with PV(it-1)
            f32x4 s0 = zero4(), s1 = zero4();
            if (haveP) {
                #pragma unroll
                for (int ks = 0; ks < 16; ++ks) {
                    bf16x8 k0 = *(const bf16x8*)&Ks[pb][c*520 + ks*32 + qd*8];
                    s0 = __builtin_amdgcn_mfma_f32_16x16x32_bf16(k0, qf[ks], s0, 0, 0, 0);
                    bf16x8 k1 = *(const bf16x8*)&Ks[pb][(16 + c)*520 + ks*32 + qd*8];
                    s1 = __builtin_amdgcn_mfma_f32_16x16x32_bf16(k1, qf[ks], s1, 0, 0, 0);
                    if (ks & 1) {
                        const int dt = ks >> 1;
                        #pragma unroll
                        for (int rt = 0; rt < 4; rt++)
                            o[dt][rt] = __builtin_amdgcn_mfma_f32_16x16x32_bf16(vf[dt], pfr[rt], o[dt][rt], 0, 0, 0);
                    }
                }
            } else {
                #pragma unroll
                for (int ks = 0; ks < 16; ++ks) {
                    bf16x8 k0 = *(const bf16x8*)&Ks[pb][c*520 + ks*32 + qd*8];
                    s0 = __builtin_amdgcn_mfma_f32_16x16x32_bf16(k0, qf[ks], s0, 0, 0, 0);
                    bf16x8 k1 = *(const bf16x8*)&Ks[pb][(16 + c)*520 + ks*32 + qd*8];
                    s1 = __builtin_amdgcn_mfma_f32_16x16x32_bf16(k1, qf[ks], s1, 0, 0, 0);
                }
            }

            // ---- mask + frozen-m softmax + publish P(it)
            const int rowg = q0 + w*16 + c;
            if (32*it + 31 > rowg) {
                const int k0g = 32*it + qd*4;
                #pragma unroll
                for (int r = 0; r < 4; r++) {
                    if (k0g + r      > rowg) s0[r] = MASKVAL;
                    if (k0g + 16 + r > rowg) s1[r] = MASKVAL;
                }
            }
            float mloc = fmaxf(fmaxf(fmaxf(s0[0], s0[1]), fmaxf(s0[2], s0[3])),
                               fmaxf(fmaxf(s1[0], s1[1]), fmaxf(s1[2], s1[3])));
            if (__ballot(mloc > m_c + 20.f)) {
                float rm = mloc;
                rm = fmaxf(rm, __shfl_xor(rm, 16));
                rm = fmaxf(rm, __shfl_xor(rm, 32));
                const float mnew = fmaxf(m_c, rm);
                const float al = exp2f((m_c - mnew) * LOG2E);
                l_c *= al;
                m_c = mnew;
                if (qd == 0) Al[pb][w*16 + c] = al;
                if (l == 0) Fl[pb][w] = 1u;
            } else {
                if (l == 0) Fl[pb][w] = 0u;
            }
            const float p0 = exp2f((s0[0] - m_c) * LOG2E);
            const float p1 = exp2f((s0[1] - m_c) * LOG2E);
            const float p2 = exp2f((s0[2] - m_c) * LOG2E);
            const float p3 = exp2f((s0[3] - m_c) * LOG2E);
            const float p4 = exp2f((s1[0] - m_c) * LOG2E);
            const float p5 = exp2f((s1[1] - m_c) * LOG2E);
            const float p6 = exp2f((s1[2] - m_c) * LOG2E);
            const float p7 = exp2f((s1[3] - m_c) * LOG2E);
            l_c += ((p0 + p1) + (p2 + p3)) + ((p4 + p5) + (p6 + p7));
            u16x4 pka, pkb;
            pka[0]=bf16bits(p0); pka[1]=bf16bits(p1); pka[2]=bf16bits(p2); pka[3]=bf16bits(p3);
            pkb[0]=bf16bits(p4); pkb[1]=bf16bits(p5); pkb[2]=bf16bits(p6); pkb[3]=bf16bits(p7);
            *(u16x4*)&Ps[pb][(w*16 + c)*40 + qd*4]      = pka;
            *(u16x4*)&Ps[pb][(w*16 + c)*40 + 16 + qd*4] = pkb;
        } else {
            // ---- PV-only path (epilogue iter or fully-masked strip)
            if (haveP) {
                #pragma unroll
                for (int dt = 0; dt < 8; dt++)
                    #pragma unroll
                    for (int rt = 0; rt < 4; rt++)
                        o[dt][rt] = __builtin_amdgcn_mfma_f32_16x16x32_bf16(vf[dt], pfr[rt], o[dt][rt], 0, 0, 0);
            }
            if (it <= it1) {        // fully-masked strip: publish zero P
                u16x4 z; z[0]=0; z[1]=0; z[2]=0; z[3]=0;
                *(u16x4*)&Ps[pb][(w*16 + c)*40 + qd*4]      = z;
                *(u16x4*)&Ps[pb][(w*16 + c)*40 + 16 + qd*4] = z;
                if (l == 0) Fl[pb][w] = 0u;
            }
        }

        // ---- issue V(it) loads for next iteration's PV (full-unit cover)
        if (it <= it1) {
            const u16* vu = Vg + (size_t)it*16384 + qd*8;
            #pragma unroll
            for (int dt = 0; dt < 8; dt++)
                vf[dt] = *(const bf16x8*)(vu + (w*128 + dt*16 + c)*32);
        }
    }

    // ---- epilogue: reduce l over qd, write m/l + unnormalized partials
    l_c += __shfl_xor(l_c, 16);
    l_c += __shfl_xor(l_c, 32);
    const size_t ob = ((size_t)((b*64 + qt)*4 + j))*64;
    if (qd == 0) {
        Mp[ob + w*16 + c] = m_c;
        Lp[ob + w*16 + c] = l_c;
    }
    #pragma unroll
    for (int dt = 0; dt < 8; dt++) {
        #pragma unroll
        for (int rt = 0; rt < 4; rt++) {
            u16x4 pk;
            pk[0] = bf16bits(o[dt][rt][0]); pk[1] = bf16bits(o[dt][rt][1]);
            pk[2] = bf16bits(o[dt][rt][2]); pk[3] = bf16bits(o[dt][rt][3]);
            *(u16x4*)&Op[(ob + rt*16 + c)*512 + w*128 + dt*16 + qd*4] = pk;
        }
    }
}

// ---------------------------------------------------------------------------
// Combine partial chunks: out = sum_j e^{m_j-M} O_j / sum_j e^{m_j-M} l_j.
// grid (64, 4) = (qt, b), 256 threads, b128 reads.
// ---------------------------------------------------------------------------
__global__ __launch_bounds__(256)
void combine(const u16* __restrict__ Op, const float* __restrict__ Mp,
             const float* __restrict__ Lp, float* __restrict__ out)
{
    __shared__ float sc[4][64];
    const int t  = threadIdx.x;
    const int qt = blockIdx.x;
    const int b  = blockIdx.y;
    const int U  = 2*qt + 2;
    const int uc = (U + 3) >> 2;
    const int nc = (U + uc - 1) / uc;          // non-empty chunks, <= 4
    const int base = (b*64 + qt)*4;

    if (t < 64) {
        float mj[4], lj[4];
        float M = MINIT;
        for (int j = 0; j < nc; j++) {
            mj[j] = Mp[(size_t)(base + j)*64 + t];
            lj[j] = Lp[(size_t)(base + j)*64 + t];
            M = fmaxf(M, mj[j]);
        }
        float denom = 0.f;
        float wj[4];
        for (int j = 0; j < nc; j++) {
            wj[j] = exp2f((mj[j] - M) * LOG2E);
            denom += wj[j] * lj[j];
        }
        const float inv = 1.0f / denom;
        for (int j = 0; j < nc; j++) sc[j][t] = wj[j] * inv;
    }
    __syncthreads();

    const int c8 = (t & 63) * 8;
    const int r0 = (t >> 6) * 16;
    for (int r = r0; r < r0 + 16; ++r) {
        float a0=0.f, a1=0.f, a2=0.f, a3=0.f, a4=0.f, a5=0.f, a6=0.f, a7=0.f;
        for (int j = 0; j < nc; j++) {
            const float s = sc[j][r];
            u16x8 v = *(const u16x8*)&Op[((size_t)(base + j)*64 + r)*512 + c8];
            a0 += s*bits2f(v[0]); a1 += s*bits2f(v[1]);
            a2 += s*bits2f(v[2]); a3 += s*bits2f(v[3]);
            a4 += s*bits2f(v[4]); a5 += s*bits2f(v[5]);
            a6 += s*bits2f(v[6]); a7 += s*bits2f(v[7]);
        }
        f32x4 ra, rb;
        ra[0]=a0; ra[1]=a1; ra[2]=a2; ra[3]=a3;
        rb[0]=a4; rb[1]=a5; rb[2]=a6; rb[3]=a7;
        float* op = &out[((size_t)(b*4096 + qt*64 + r))*512 + c8];
        *(f32x4*)op       = ra;
        *(f32x4*)(op + 4) = rb;
    }
}

extern "C" void kernel_launch(void* const* d_in, const int* in_sizes, int n_in,
                              void* d_out, int out_size, void* d_ws, size_t ws_size,
                              hipStream_t stream)
{
    (void)in_sizes; (void)n_in; (void)out_size; (void)ws_size;
    const float* X  = (const float*)d_in[0];
    const float* WQ = (const float*)d_in[1];
    const float* WK = (const float*)d_in[2];
    const float* WV = (const float*)d_in[3];
    float* out = (float*)d_out;
    char* ws = (char*)d_ws;
    const size_t MB = 1024*1024;
    u16*   Qb = (u16*)(ws);                    // [0,16) MB  bf16 [16384][512], Q pre-scaled
    u16*   Kb = (u16*)(ws + 16*MB);            // [16,32) MB bf16 [16384][512]
    u16*   Vt = (u16*)(ws + 32*MB);            // [32,48) MB bf16 V^T [4][128][512][32]
    u16*   Wb = (u16*)(ws + 48*MB);            // 1.5 MB bf16 [1536][512]
    float* Mp = (float*)(ws + 50*MB);          // 256 KB [4][64][4][64]
    float* Lp = (float*)(ws + 51*MB);          // 256 KB
    u16*   Op = (u16*)(ws + 52*MB);            // 64 MB bf16 [4][64][4][64][512] -> ws 116 MB
    u16*   Xb = (u16*)(ws + 52*MB);            // 16 MB, ALIASES Op (gemm phase only)

    convert_w<<<dim3(384), 256, 0, stream>>>(WQ, WK, WV, Wb);
    convert_x<<<dim3(4096), 256, 0, stream>>>(X, Xb);
    gemm_qkv<<<dim3(12, 128), 256, 0, stream>>>(Xb, Wb, Qb, Kb, Vt);
    attn_chunk<<<dim3(1024), 256, 0, stream>>>(Qb, Kb, Vt, Op, Mp, Lp);
    combine<<<dim3(64, 4), 256, 0, stream>>>(Op, Mp, Lp, out);
}

// Round 10
// 299.106 us; speedup vs baseline: 2.7986x; 2.7986x over previous
//
#include <hip/hip_runtime.h>

typedef __attribute__((ext_vector_type(8))) __bf16 bf16x8;
typedef __attribute__((ext_vector_type(4))) float f32x4;
typedef unsigned short u16;
typedef __attribute__((ext_vector_type(4))) u16 u16x4;
typedef __attribute__((ext_vector_type(8))) u16 u16x8;

#define MASKVAL -3.0e38f
#define MINIT   -1.0e38f
#define LOG2E 1.4426950408889634f

__device__ inline f32x4 zero4() { f32x4 v; v[0]=0.f; v[1]=0.f; v[2]=0.f; v[3]=0.f; return v; }

__device__ inline u16 bf16bits(float x) {
    union { __bf16 h; u16 u; } cv; cv.h = (__bf16)x; return cv.u;
}
__device__ inline float bits2f(u16 b) {
    union { unsigned u; float f; } cv; cv.u = ((unsigned)b) << 16; return cv.f;
}

// async 16B/lane global -> LDS (lds dest = wave-uniform base + lane*16)
__device__ inline void load_lds16(const u16* g, u16* l) {
    __builtin_amdgcn_global_load_lds((const __attribute__((address_space(1))) void*)g,
                                     (__attribute__((address_space(3))) void*)l, 16, 0, 0);
}

// ---------------------------------------------------------------------------
// Convert W_Q (pre-scaled by 1/sqrt(512)), W_K, W_V to bf16 concat [1536][512].
// ---------------------------------------------------------------------------
__global__ void convert_w(const float* __restrict__ WQ, const float* __restrict__ WK,
                          const float* __restrict__ WV, u16* __restrict__ Wb)
{
    const float qscale = 0.044194173824159216f;  // 1/sqrt(512)
    const int i8 = (blockIdx.x * 256 + threadIdx.x) * 8;
    const int seg = i8 >> 18;                    // 262144 els per W
    const int within = i8 & 262143;
    const float* src = (seg == 0) ? WQ : (seg == 1) ? WK : WV;
    const float sc = (seg == 0) ? qscale : 1.0f;
    f32x4 a = *(const f32x4*)(src + within);
    f32x4 b = *(const f32x4*)(src + within + 4);
    bf16x8 v;
    v[0]=(__bf16)(a[0]*sc); v[1]=(__bf16)(a[1]*sc); v[2]=(__bf16)(a[2]*sc); v[3]=(__bf16)(a[3]*sc);
    v[4]=(__bf16)(b[0]*sc); v[5]=(__bf16)(b[1]*sc); v[6]=(__bf16)(b[2]*sc); v[7]=(__bf16)(b[3]*sc);
    *(bf16x8*)(Wb + i8) = v;
}

// ---------------------------------------------------------------------------
// Convert X f32 -> bf16. 16384*512 = 8,388,608 els = 4096 blocks x 256 x 8.
// ---------------------------------------------------------------------------
__global__ void convert_x(const float* __restrict__ X, u16* __restrict__ Xb)
{
    const size_t i8 = ((size_t)blockIdx.x * 256 + threadIdx.x) * 8;
    f32x4 a = *(const f32x4*)(X + i8);
    f32x4 b = *(const f32x4*)(X + i8 + 4);
    bf16x8 v;
    v[0]=(__bf16)a[0]; v[1]=(__bf16)a[1]; v[2]=(__bf16)a[2]; v[3]=(__bf16)a[3];
    v[4]=(__bf16)b[0]; v[5]=(__bf16)b[1]; v[6]=(__bf16)b[2]; v[7]=(__bf16)b[3];
    *(bf16x8*)(Xb + i8) = v;
}

// ---------------------------------------------------------------------------
// GEMM: Q/K [16384][512] bf16; V^T tiled [b][u32 (128)][512 d][32 k] bf16.
// A = Xb bf16, B = Wb bf16, both staged via global_load_lds width-16.
// 128x128 tile, BK=32, 4 waves. grid = (12, 128): x: 0-3 Q, 4-7 K, 8-11 V.
// ---------------------------------------------------------------------------
__global__ __launch_bounds__(256, 2)
void gemm_qkv(const u16* __restrict__ Xb, const u16* __restrict__ Wb,
              u16* __restrict__ Qb, u16* __restrict__ Kb, u16* __restrict__ Vt)
{
    __shared__ u16 As[128*32];
    __shared__ u16 Bs[128*32];
    const int t  = threadIdx.x;
    const int l  = t & 63;
    const int w  = t >> 6;
    const int c  = l & 15;
    const int qd = l >> 4;
    const int m0 = blockIdx.y * 128;
    const int nblk = blockIdx.x;
    const int n0 = nblk * 128;                  // row into Wb[1536]
    const int seg = nblk >> 2;
    const int nw0 = (nblk & 3) * 128;           // feature offset within a W
    const int wm = w >> 1, wn = w & 1;
    const int lr = l >> 2;                      // 0..15 row-within-instr
    const int lc = (l & 3) * 8;                 // 8-el chunk

    f32x4 acc[4][4];
    #pragma unroll
    for (int i = 0; i < 4; i++)
        #pragma unroll
        for (int j = 0; j < 4; j++) acc[i][j] = zero4();

    for (int kk = 0; kk < 512; kk += 32) {
        #pragma unroll
        for (int i = 0; i < 2; ++i) {
            const int r0 = w*32 + i*16;
            load_lds16(&Xb[(size_t)(m0 + r0 + lr)*512 + kk + lc], &As[r0*32]);
            load_lds16(&Wb[(size_t)(n0 + r0 + lr)*512 + kk + lc], &Bs[r0*32]);
        }
        __syncthreads();
        bf16x8 af[4], bfr[4];
        #pragma unroll
        for (int mt = 0; mt < 4; mt++) af[mt]  = *(const bf16x8*)&As[(wm*64 + mt*16 + c)*32 + qd*8];
        #pragma unroll
        for (int nt = 0; nt < 4; nt++) bfr[nt] = *(const bf16x8*)&Bs[(wn*64 + nt*16 + c)*32 + qd*8];
        #pragma unroll
        for (int mt = 0; mt < 4; mt++)
            #pragma unroll
            for (int nt = 0; nt < 4; nt++)
                acc[mt][nt] = __builtin_amdgcn_mfma_f32_16x16x32_bf16(af[mt], bfr[nt], acc[mt][nt], 0, 0, 0);
        __syncthreads();
    }

    #pragma unroll
    for (int mt = 0; mt < 4; mt++) {
        #pragma unroll
        for (int nt = 0; nt < 4; nt++) {
            const int gm0 = m0 + wm*64 + mt*16 + qd*4;       // token row of reg 0
            const int gn  = nw0 + wn*64 + nt*16 + c;         // feature 0..511
            if (seg == 0) {
                #pragma unroll
                for (int r = 0; r < 4; r++)
                    Qb[(size_t)(gm0 + r)*512 + gn] = bf16bits(acc[mt][nt][r]);
            } else if (seg == 1) {
                #pragma unroll
                for (int r = 0; r < 4; r++)
                    Kb[(size_t)(gm0 + r)*512 + gn] = bf16bits(acc[mt][nt][r]);
            } else {
                const int bb   = gm0 >> 12;
                const int ss   = gm0 & 4095;
                const int unit = ss >> 5;                    // 32-key unit
                const int kl   = ss & 31;                    // 4-aligned
                u16x4 pk;
                pk[0] = bf16bits(acc[mt][nt][0]);
                pk[1] = bf16bits(acc[mt][nt][1]);
                pk[2] = bf16bits(acc[mt][nt][2]);
                pk[3] = bf16bits(acc[mt][nt][3]);
                *(u16x4*)&Vt[((size_t)(bb*128 + unit)*512 + gn)*32 + kl] = pk;
            }
        }
    }
}

// ---------------------------------------------------------------------------
// Flash attention chunk v10 = v7 body verbatim (register-safe local optimum:
// V loads after barrier, consumed same iteration -- values held across the
// barrier spill to scratch, see R9 post-mortem). R7 chunking: 1024 blocks,
// 4 chunks/qt (uc = ceil(U/4)), heavy-first, dynamic backfill -> 2 blocks/CU.
// Unit = 32 keys. S^T = K Q^T per 16-row strip; PV d-split (wave w covers
// d in [128w,128w+128)) with P broadcast via LDS dbuf; V per-wave from
// global (b128, L2-hot); K dbuf via global_load_lds; one barrier per unit;
// frozen-m softmax with ballot-guarded rescale.
// ---------------------------------------------------------------------------
__global__ __launch_bounds__(256, 2)
void attn_chunk(const u16* __restrict__ Qb, const u16* __restrict__ Kb,
                const u16* __restrict__ Vt, u16* __restrict__ Op,
                float* __restrict__ Mp, float* __restrict__ Lp)
{
    __shared__ u16 Ks[2][32*520];   // 66,560 B  K rows padded 520 (1KB contiguous)
    __shared__ u16 Ps[2][64*40];    // 10,240 B  P[row][32 keys + pad 8]
    __shared__ float Al[2][64];     //  512 B    per-row alpha (slow path)
    __shared__ unsigned Fl[2][4];   //   32 B    per-strip rescale flag

    const int t  = threadIdx.x;
    const int l  = t & 63;
    const int w  = t >> 6;
    const int c  = l & 15;
    const int qd = l >> 4;
    const int x  = blockIdx.x;
    const int qt = 63 - (x >> 4);
    const int j  = (x >> 2) & 3;
    const int b  = x & 3;
    const int U  = 2*qt + 2;                 // 32-key units total
    const int uc = (U + 3) >> 2;
    const int it0 = j * uc;
    if (it0 >= U) return;
    const int it1 = min(U, it0 + uc) - 1;
    const int q0 = qt * 64;
    const int itSkip = 2*qt + (w >> 1);      // last unit with any valid key for strip w

    // Q fragments (B-operand: n=row=c, k=qd*8+jj), register-resident
    bf16x8 qf[16];
    {
        const size_t qrow = (size_t)(b*4096 + q0 + w*16 + c);
        #pragma unroll
        for (int ks = 0; ks < 16; ++ks)
            qf[ks] = *(const bf16x8*)&Qb[qrow*512 + ks*32 + qd*8];
    }

    f32x4 o[8][4];                  // [dt][rt]: d = w*128+dt*16+qd*4+r, row = rt*16+c
    #pragma unroll
    for (int dt = 0; dt < 8; dt++)
        #pragma unroll
        for (int rt = 0; rt < 4; rt++) o[dt][rt] = zero4();
    float m_c = MINIT, l_c = 0.f;

    const u16* Kg = Kb + (size_t)(b*4096)*512;
    const u16* Vg = Vt + (size_t)(b*128)*16384;

    // prologue: stage K(it0); wave w stages key-rows [8w, 8w+8)
    #pragma unroll
    for (int i = 0; i < 8; i++) {
        const int row = w*8 + i;
        load_lds16(Kg + ((size_t)(it0*32 + row))*512 + l*8, &Ks[0][row*520]);
    }

    for (int it = it0; it <= it1 + 1; ++it) {
        const int pb = (it - it0) & 1;
        __syncthreads();            // K(it) staged; P(it-1)/Al/Fl published

        // ---- V loads for PV(it-1): 8 coalesced b128, own d-quarter
        bf16x8 vf[8];
        if (it > it0) {
            const u16* vu = Vg + (size_t)(it-1)*16384 + qd*8;
            #pragma unroll
            for (int dt = 0; dt < 8; dt++)
                vf[dt] = *(const bf16x8*)(vu + (w*128 + dt*16 + c)*32);
        }
        // ---- issue K staging (it+1)
        if (it < it1) {
            #pragma unroll
            for (int i = 0; i < 8; i++) {
                const int row = w*8 + i;
                load_lds16(Kg + ((size_t)((it+1)*32 + row))*512 + l*8, &Ks[pb^1][row*520]);
            }
        }

        // ---- S^T + softmax for unit it
        if (it <= it1) {
            if (it <= itSkip) {
                f32x4 s0 = zero4(), s1 = zero4();
                #pragma unroll
                for (int ks = 0; ks < 16; ++ks) {
                    bf16x8 k0 = *(const bf16x8*)&Ks[pb][c*520 + ks*32 + qd*8];
                    s0 = __builtin_amdgcn_mfma_f32_16x16x32_bf16(k0, qf[ks], s0, 0, 0, 0);
                    bf16x8 k1 = *(const bf16x8*)&Ks[pb][(16 + c)*520 + ks*32 + qd*8];
                    s1 = __builtin_amdgcn_mfma_f32_16x16x32_bf16(k1, qf[ks], s1, 0, 0, 0);
                }
                const int rowg = q0 + w*16 + c;
                if (32*it + 31 > rowg) {       // causal mask (partial unit)
                    const int k0g = 32*it + qd*4;
                    #pragma unroll
                    for (int r = 0; r < 4; r++) {
                        if (k0g + r      > rowg) s0[r] = MASKVAL;
                        if (k0g + 16 + r > rowg) s1[r] = MASKVAL;
                    }
                }
                float mloc = fmaxf(fmaxf(fmaxf(s0[0], s0[1]), fmaxf(s0[2], s0[3])),
                                   fmaxf(fmaxf(s1[0], s1[1]), fmaxf(s1[2], s1[3])));
                if (__ballot(mloc > m_c + 20.f)) {   // slow path (first unit + rare drift)
                    float rm = mloc;
                    rm = fmaxf(rm, __shfl_xor(rm, 16));
                    rm = fmaxf(rm, __shfl_xor(rm, 32));
                    const float mnew = fmaxf(m_c, rm);
                    const float al = exp2f((m_c - mnew) * LOG2E);
                    l_c *= al;
                    m_c = mnew;
                    if (qd == 0) Al[pb][w*16 + c] = al;
                    if (l == 0) Fl[pb][w] = 1u;
                } else {
                    if (l == 0) Fl[pb][w] = 0u;
                }
                const float p0 = exp2f((s0[0] - m_c) * LOG2E);
                const float p1 = exp2f((s0[1] - m_c) * LOG2E);
                const float p2 = exp2f((s0[2] - m_c) * LOG2E);
                const float p3 = exp2f((s0[3] - m_c) * LOG2E);
                const float p4 = exp2f((s1[0] - m_c) * LOG2E);
                const float p5 = exp2f((s1[1] - m_c) * LOG2E);
                const float p6 = exp2f((s1[2] - m_c) * LOG2E);
                const float p7 = exp2f((s1[3] - m_c) * LOG2E);
                l_c += ((p0 + p1) + (p2 + p3)) + ((p4 + p5) + (p6 + p7));
                u16x4 pka, pkb;
                pka[0]=bf16bits(p0); pka[1]=bf16bits(p1); pka[2]=bf16bits(p2); pka[3]=bf16bits(p3);
                pkb[0]=bf16bits(p4); pkb[1]=bf16bits(p5); pkb[2]=bf16bits(p6); pkb[3]=bf16bits(p7);
                *(u16x4*)&Ps[pb][(w*16 + c)*40 + qd*4]      = pka;
                *(u16x4*)&Ps[pb][(w*16 + c)*40 + 16 + qd*4] = pkb;
            } else {
                // fully-masked unit for this strip: publish zero P, no rescale
                u16x4 z; z[0]=0; z[1]=0; z[2]=0; z[3]=0;
                *(u16x4*)&Ps[pb][(w*16 + c)*40 + qd*4]      = z;
                *(u16x4*)&Ps[pb][(w*16 + c)*40 + 16 + qd*4] = z;
                if (l == 0) Fl[pb][w] = 0u;
            }
        }

        // ---- PV(it-1): o[dt][rt] += V^T-frag x P-frag (K=32)
        if (it > it0) {
            const int ppb = pb ^ 1;
            bf16x8 pfr[4];
            #pragma unroll
            for (int rt = 0; rt < 4; rt++)
                pfr[rt] = *(const bf16x8*)&Ps[ppb][(rt*16 + c)*40 + qd*8];
            #pragma unroll
            for (int rt = 0; rt < 4; rt++) {
                if (Fl[ppb][rt]) {
                    const float al = Al[ppb][rt*16 + c];
                    #pragma unroll
                    for (int dt = 0; dt < 8; dt++) {
                        o[dt][rt][0] *= al; o[dt][rt][1] *= al;
                        o[dt][rt][2] *= al; o[dt][rt][3] *= al;
                    }
                }
            }
            #pragma unroll
            for (int dt = 0; dt < 8; dt++)
                #pragma unroll
                for (int rt = 0; rt < 4; rt++)
                    o[dt][rt] = __builtin_amdgcn_mfma_f32_16x16x32_bf16(vf[dt], pfr[rt], o[dt][rt], 0, 0, 0);
        }
    }

    // ---- epilogue: reduce l over qd, write m/l + unnormalized partials
    l_c += __shfl_xor(l_c, 16);
    l_c += __shfl_xor(l_c, 32);
    const size_t ob = ((size_t)((b*64 + qt)*4 + j))*64;
    if (qd == 0) {
        Mp[ob + w*16 + c] = m_c;
        Lp[ob + w*16 + c] = l_c;
    }
    #pragma unroll
    for (int dt = 0; dt < 8; dt++) {
        #pragma unroll
        for (int rt = 0; rt < 4; rt++) {
            u16x4 pk;
            pk[0] = bf16bits(o[dt][rt][0]); pk[1] = bf16bits(o[dt][rt][1]);
            pk[2] = bf16bits(o[dt][rt][2]); pk[3] = bf16bits(o[dt][rt][3]);
            *(u16x4*)&Op[(ob + rt*16 + c)*512 + w*128 + dt*16 + qd*4] = pk;
        }
    }
}

// ---------------------------------------------------------------------------
// Combine partial chunks: out = sum_j e^{m_j-M} O_j / sum_j e^{m_j-M} l_j.
// grid (64, 4) = (qt, b), 256 threads, b128 reads.
// ---------------------------------------------------------------------------
__global__ __launch_bounds__(256)
void combine(const u16* __restrict__ Op, const float* __restrict__ Mp,
             const float* __restrict__ Lp, float* __restrict__ out)
{
    __shared__ float sc[4][64];
    const int t  = threadIdx.x;
    const int qt = blockIdx.x;
    const int b  = blockIdx.y;
    const int U  = 2*qt + 2;
    const int uc = (U + 3) >> 2;
    const int nc = (U + uc - 1) / uc;          // non-empty chunks, <= 4
    const int base = (b*64 + qt)*4;

    if (t < 64) {
        float mj[4], lj[4];
        float M = MINIT;
        for (int j = 0; j < nc; j++) {
            mj[j] = Mp[(size_t)(base + j)*64 + t];
            lj[j] = Lp[(size_t)(base + j)*64 + t];
            M = fmaxf(M, mj[j]);
        }
        float denom = 0.f;
        float wj[4];
        for (int j = 0; j < nc; j++) {
            wj[j] = exp2f((mj[j] - M) * LOG2E);
            denom += wj[j] * lj[j];
        }
        const float inv = 1.0f / denom;
        for (int j = 0; j < nc; j++) sc[j][t] = wj[j] * inv;
    }
    __syncthreads();

    const int c8 = (t & 63) * 8;
    const int r0 = (t >> 6) * 16;
    for (int r = r0; r < r0 + 16; ++r) {
        float a0=0.f, a1=0.f, a2=0.f, a3=0.f, a4=0.f, a5=0.f, a6=0.f, a7=0.f;
        for (int j = 0; j < nc; j++) {
            const float s = sc[j][r];
            u16x8 v = *(const u16x8*)&Op[((size_t)(base + j)*64 + r)*512 + c8];
            a0 += s*bits2f(v[0]); a1 += s*bits2f(v[1]);
            a2 += s*bits2f(v[2]); a3 += s*bits2f(v[3]);
            a4 += s*bits2f(v[4]); a5 += s*bits2f(v[5]);
            a6 += s*bits2f(v[6]); a7 += s*bits2f(v[7]);
        }
        f32x4 ra, rb;
        ra[0]=a0; ra[1]=a1; ra[2]=a2; ra[3]=a3;
        rb[0]=a4; rb[1]=a5; rb[2]=a6; rb[3]=a7;
        float* op = &out[((size_t)(b*4096 + qt*64 + r))*512 + c8];
        *(f32x4*)op       = ra;
        *(f32x4*)(op + 4) = rb;
    }
}

extern "C" void kernel_launch(void* const* d_in, const int* in_sizes, int n_in,
                              void* d_out, int out_size, void* d_ws, size_t ws_size,
                              hipStream_t stream)
{
    (void)in_sizes; (void)n_in; (void)out_size; (void)ws_size;
    const float* X  = (const float*)d_in[0];
    const float* WQ = (const float*)d_in[1];
    const float* WK = (const float*)d_in[2];
    const float* WV = (const float*)d_in[3];
    float* out = (float*)d_out;
    char* ws = (char*)d_ws;
    const size_t MB = 1024*1024;
    u16*   Qb = (u16*)(ws);                    // [0,16) MB  bf16 [16384][512], Q pre-scaled
    u16*   Kb = (u16*)(ws + 16*MB);            // [16,32) MB bf16 [16384][512]
    u16*   Vt = (u16*)(ws + 32*MB);            // [32,48) MB bf16 V^T [4][128][512][32]
    u16*   Wb = (u16*)(ws + 48*MB);            // 1.5 MB bf16 [1536][512]
    float* Mp = (float*)(ws + 50*MB);          // 256 KB [4][64][4][64]
    float* Lp = (float*)(ws + 51*MB);          // 256 KB
    u16*   Op = (u16*)(ws + 52*MB);            // 64 MB bf16 [4][64][4][64][512] -> ws 116 MB
    u16*   Xb = (u16*)(ws + 52*MB);            // 16 MB, ALIASES Op (gemm phase only)

    convert_w<<<dim3(384), 256, 0, stream>>>(WQ, WK, WV, Wb);
    convert_x<<<dim3(4096), 256, 0, stream>>>(X, Xb);
    gemm_qkv<<<dim3(12, 128), 256, 0, stream>>>(Xb, Wb, Qb, Kb, Vt);
    attn_chunk<<<dim3(1024), 256, 0, stream>>>(Qb, Kb, Vt, Op, Mp, Lp);
    combine<<<dim3(64, 4), 256, 0, stream>>>(Op, Mp, Lp, out);
}